// Round 6
// baseline (803.542 us; speedup 1.0000x reference)
//
#include <hip/hip_runtime.h>

typedef short s16x8 __attribute__((ext_vector_type(8)));
typedef float f32x4 __attribute__((ext_vector_type(4)));
typedef unsigned short u16;

static __device__ __forceinline__ f32x4 mfma16(s16x8 a, s16x8 b, f32x4 c) {
  return __builtin_amdgcn_mfma_f32_16x16x32_bf16(a, b, c, 0, 0, 0);
}

// fp32 -> bf16 round-to-nearest-even
static __device__ __forceinline__ u16 f2b(float f) {
  union { float f; unsigned int u; } v; v.f = f;
  unsigned int u = v.u;
  return (u16)((u + 0x7fffu + ((u >> 16) & 1u)) >> 16);
}
static __device__ __forceinline__ float b2f(u16 h) {
  union { float f; unsigned int u; } v; v.u = ((unsigned int)h) << 16;
  return v.f;
}

// async global->LDS, 16B per lane; LDS dest = wave-uniform base + lane*16
static __device__ __forceinline__ void gld_lds16(const void* g, void* l) {
  __builtin_amdgcn_global_load_lds(
      (const __attribute__((address_space(1))) void*)g,
      (__attribute__((address_space(3))) void*)l, 16, 0, 0);
}

// wave-parallel 512-dot: lane owns 8 consecutive elements; full-wave reduce.
static __device__ __forceinline__ float wdot512(const float* __restrict__ row,
                                                const float* __restrict__ vl,
                                                int lane) {
  const float4* r4 = (const float4*)row;
  const float4* v4 = (const float4*)vl;
  const float4 a0 = r4[lane << 1], a1 = r4[(lane << 1) + 1];
  const float4 b0 = v4[lane << 1], b1 = v4[(lane << 1) + 1];
  float s = a0.x*b0.x + a0.y*b0.y + a0.z*b0.z + a0.w*b0.w
          + a1.x*b1.x + a1.y*b1.y + a1.z*b1.z + a1.w*b1.w;
  s += __shfl_xor(s, 1);  s += __shfl_xor(s, 2);  s += __shfl_xor(s, 4);
  s += __shfl_xor(s, 8);  s += __shfl_xor(s, 16); s += __shfl_xor(s, 32);
  return s;
}

// ---------------------------------------------------------------------------
// 64x64 GEMM tile from fp32 inputs (bf16-staged, fp32 acc).
// MODE 0: bf16 store; MODE 3: fp32 store. Full tile in-bounds, K%32==0.
// ---------------------------------------------------------------------------
template<int MODE>
static __device__ void gemm_tile(const float* __restrict__ A,
                                 const float* __restrict__ B,
                                 void* __restrict__ Cout,
                                 int m0, int n0, int K, int lda, int ldb, int ldc,
                                 u16 (*As)[40], u16 (*BsT)[40]) {
  const int tid = threadIdx.x;
  const int wave = tid >> 6, lane = tid & 63;
  const int quad = lane >> 4, l16 = lane & 15;
  f32x4 acc[4] = {{0,0,0,0},{0,0,0,0},{0,0,0,0},{0,0,0,0}};
  for (int k0 = 0; k0 < K; k0 += 32) {
    __syncthreads();
    { // stage A tile 64x32
      const int r = tid >> 2, cs = (tid & 3) << 3;
      const float* ap = A + (size_t)(m0 + r) * lda + k0 + cs;
      float4 v0 = *(const float4*)ap, v1 = *(const float4*)(ap + 4);
      As[r][cs+0] = f2b(v0.x); As[r][cs+1] = f2b(v0.y);
      As[r][cs+2] = f2b(v0.z); As[r][cs+3] = f2b(v0.w);
      As[r][cs+4] = f2b(v1.x); As[r][cs+5] = f2b(v1.y);
      As[r][cs+6] = f2b(v1.z); As[r][cs+7] = f2b(v1.w);
    }
    { // stage B tile 32x64 transposed -> BsT[n][k]
      const int kk = tid >> 3, ns = (tid & 7) << 3;
      const float* bp = B + (size_t)(k0 + kk) * ldb + n0 + ns;
      float4 v0 = *(const float4*)bp, v1 = *(const float4*)(bp + 4);
      BsT[ns+0][kk] = f2b(v0.x); BsT[ns+1][kk] = f2b(v0.y);
      BsT[ns+2][kk] = f2b(v0.z); BsT[ns+3][kk] = f2b(v0.w);
      BsT[ns+4][kk] = f2b(v1.x); BsT[ns+5][kk] = f2b(v1.y);
      BsT[ns+6][kk] = f2b(v1.z); BsT[ns+7][kk] = f2b(v1.w);
    }
    __syncthreads();
    const s16x8 af = *(const s16x8*)&As[(wave << 4) + l16][quad << 3];
    #pragma unroll
    for (int nt = 0; nt < 4; nt++) {
      const s16x8 bfr = *(const s16x8*)&BsT[(nt << 4) + l16][quad << 3];
      acc[nt] = mfma16(af, bfr, acc[nt]);
    }
  }
  const int mrow = m0 + (wave << 4) + (quad << 2);
  #pragma unroll
  for (int nt = 0; nt < 4; nt++) {
    const int n = n0 + (nt << 4) + l16;
    #pragma unroll
    for (int r = 0; r < 4; r++) {
      const float v = acc[nt][r];
      if (MODE == 0) ((u16*)Cout)[(size_t)(mrow + r) * ldc + n] = f2b(v);
      else           ((float*)Cout)[(size_t)(mrow + r) * ldc + n] = v;
    }
  }
}

// ---------------------------------------------------------------------------
// Launch 1: ALL precompute + fp32->bf16 conversion (grid-stride), one dispatch.
// blocks [0,96)    : Wq_eff bf16   [96,192): Wk_eff bf16   [192,288): Wv_eff f32
// blocks [288,320) : Wf = Wout@Wo f32
// block  320       : bias chains, WAVE-PARALLEL dots (was the 150us serial tail)
// blocks [321,2369): grid-stride conversion chunk fp32 -> Xb bf16 (pad rows 0)
// ---------------------------------------------------------------------------
__global__ __launch_bounds__(256)
void prep_all(const float* __restrict__ chunk,
              const float* __restrict__ Wq, const float* __restrict__ bq,
              const float* __restrict__ Wk, const float* __restrict__ bk,
              const float* __restrict__ Wv, const float* __restrict__ bv,
              const float* __restrict__ W_in, const float* __restrict__ b_in,
              const float* __restrict__ Wo, const float* __restrict__ bo,
              const float* __restrict__ Wout, const float* __restrict__ bout,
              u16* __restrict__ Wqkv, float* __restrict__ Wv_eff,
              float* __restrict__ Wf, float* __restrict__ b_eff,
              float* __restrict__ b2, u16* __restrict__ Xb) {
  __shared__ u16 As[64][40];
  __shared__ u16 BsT[64][40];
  __shared__ float vq[512], vk[512], vv[512], vt[512], vt2[512];
  const int b = blockIdx.x;
  const int tid = threadIdx.x;

  if (b < 96) {
    gemm_tile<0>(W_in, Wq, Wqkv, (b / 12) << 6, (b % 12) << 6, 512, 512, 768, 768, As, BsT);
  } else if (b < 192) {
    const int bb = b - 96;
    gemm_tile<0>(W_in + 512 * 512, Wk, Wqkv + 512 * 768,
                 (bb / 12) << 6, (bb % 12) << 6, 512, 512, 768, 768, As, BsT);
  } else if (b < 288) {
    const int bb = b - 192;
    gemm_tile<3>(W_in + 1024 * 512, Wv, Wv_eff,
                 (bb / 12) << 6, (bb % 12) << 6, 512, 512, 768, 768, As, BsT);
  } else if (b < 320) {
    const int bb = b - 288;
    gemm_tile<3>(Wout, Wo, Wf, (bb / 8) << 6, (bb % 8) << 6, 512, 512, 512, 512, As, BsT);
  } else if (b == 320) {
    // bias chains, one wave per 512-dot (64 lanes x 8 elems), phases sync'd.
    const int wv = tid >> 6, ln = tid & 63;
    for (int j = tid; j < 512; j += 256) {
      vq[j] = bq[j]; vk[j] = bk[j]; vv[j] = bv[j];
    }
    __syncthreads();
    // phase A (independent): b_eff[0:512]=W_in_q@bq, b_eff[512:1024]=W_in_k@bk,
    //                        t1 = W_in_v@bv   (+b_in)
    for (int j = wv; j < 1536; j += 4) {
      const float* vsel = (j < 512) ? vq : ((j < 1024) ? vk : vv);
      const float s = wdot512(W_in + (size_t)j * 512, vsel, ln);
      if (ln == 0) {
        const float val = s + b_in[j];
        if (j < 1024) b_eff[j] = val;
        else          vt[j - 1024] = val;
      }
    }
    __syncthreads();
    // phase B: t2 = Wo @ t1 + bo
    for (int j = wv; j < 512; j += 4) {
      const float s = wdot512(Wo + (size_t)j * 512, vt, ln);
      if (ln == 0) vt2[j] = s + bo[j];
    }
    __syncthreads();
    // phase C: b2 = Wout @ t2 + bout
    for (int j = wv; j < 256; j += 4) {
      const float s = wdot512(Wout + (size_t)j * 512, vt2, ln);
      if (ln == 0) b2[j] = s + bout[j];
    }
  } else {
    // grid-stride conversion: 2048 blocks cover 50048*768/8 = 4804608 groups
    const size_t stride = 2048 * 256;
    for (size_t g = (size_t)(b - 321) * 256 + tid; g < 4804608ull; g += stride) {
      const size_t i = g << 3;
      ushort4 lo, hi;
      if (i < (size_t)50000 * 768) {
        const float4 a = *(const float4*)(chunk + i);
        const float4 bb = *(const float4*)(chunk + i + 4);
        lo.x = f2b(a.x); lo.y = f2b(a.y); lo.z = f2b(a.z); lo.w = f2b(a.w);
        hi.x = f2b(bb.x); hi.y = f2b(bb.y); hi.z = f2b(bb.z); hi.w = f2b(bb.w);
      } else {
        lo.x = lo.y = lo.z = lo.w = 0; hi.x = hi.y = hi.z = hi.w = 0;
      }
      *(ushort4*)(Xb + i) = lo;
      *(ushort4*)(Xb + i + 4) = hi;
    }
  }
}

// ---------------------------------------------------------------------------
// Launch 2: QK projection (3128 blocks, XCD-band swizzle) + Mh tiles (384).
// ---------------------------------------------------------------------------
__global__ __launch_bounds__(256)
void qk_mh(const u16* __restrict__ Xb, const u16* __restrict__ W,
           const float* __restrict__ bias, u16* __restrict__ QK2,
           const float* __restrict__ Wf, const float* __restrict__ Wv_eff,
           u16* __restrict__ Mh) {
  __shared__ char smem[16384];
  const int gb = blockIdx.x;
  const int tid = threadIdx.x;

  if (gb >= 3128) {
    const int bb = gb - 3128;           // [0,384)
    const int z = bb / 48, r = bb % 48;
    u16 (*As40)[40] = (u16(*)[40])smem;
    u16 (*Bs40)[40] = (u16(*)[40])(smem + 5120);
    gemm_tile<0>(Wf + z * 64, Wv_eff + (size_t)z * 64 * 768, Mh + z * 768,
                 (r / 12) << 6, (r % 12) << 6, 64, 512, 768, 6144, As40, Bs40);
    return;
  }

  u16* As = (u16*)smem;
  u16* Bs = (u16*)(smem + 8192);
  const int xcd = gb & 7;
  const int lin = xcd * 391 + (gb >> 3);
  const int n0 = (lin & 7) << 7;
  const int m0 = (lin >> 3) << 7;
  const int wave = tid >> 6, lane = tid & 63;
  const int wm = wave >> 1, wn = wave & 1;
  const int quad = lane >> 4, l16 = lane & 15;

  const int r0 = (wave << 5) + (lane >> 2);
  const int cb = (lane & 3) << 3;
  const u16* gA = Xb + (size_t)(m0 + r0) * 768 + cb;
  const u16* gB = W  + (size_t)(n0 + r0) * 768 + cb;
  u16* lA = As + (wave << 10);
  u16* lB = Bs + (wave << 10);

  f32x4 acc[4][4];
  #pragma unroll
  for (int i = 0; i < 4; i++)
    #pragma unroll
    for (int j = 0; j < 4; j++) acc[i][j] = (f32x4){0.f, 0.f, 0.f, 0.f};

  for (int k0 = 0; k0 < 768; k0 += 32) {
    __syncthreads();
    gld_lds16(gA + k0,            lA);
    gld_lds16(gA + k0 + 16 * 768, lA + 512);
    gld_lds16(gB + k0,            lB);
    gld_lds16(gB + k0 + 16 * 768, lB + 512);
    __syncthreads();
    s16x8 af[4], bf[4];
    #pragma unroll
    for (int i = 0; i < 4; i++)
      af[i] = *(const s16x8*)(As + ((wm << 6) + (i << 4) + l16) * 32 + (quad << 3));
    #pragma unroll
    for (int j = 0; j < 4; j++)
      bf[j] = *(const s16x8*)(Bs + ((wn << 6) + (j << 4) + l16) * 32 + (quad << 3));
    #pragma unroll
    for (int i = 0; i < 4; i++)
      #pragma unroll
      for (int j = 0; j < 4; j++)
        acc[i][j] = mfma16(af[i], bf[j], acc[i][j]);
  }

  #pragma unroll
  for (int j = 0; j < 4; j++) {
    const int col = n0 + (wn << 6) + (j << 4) + l16;
    const float badd = bias[col];
    #pragma unroll
    for (int i = 0; i < 4; i++) {
      const int row = m0 + (wm << 6) + (i << 4) + (quad << 2);
      #pragma unroll
      for (int r = 0; r < 4; r++)
        QK2[(size_t)(row + r) * 1024 + col] = f2b(acc[i][j][r] + badd);
    }
  }
}

// ---------------------------------------------------------------------------
// Per-wave, per-head: S = QK^T (MFMA, frags from global), softmax + column
// sums entirely in registers (16-lane shfl for rows, xor 16/32 for columns).
// ---------------------------------------------------------------------------
template<int MT>
static __device__ __forceinline__ void head_sw(
    const u16* __restrict__ QK2, const int* __restrict__ idx_s,
    float* __restrict__ wl, const int h, const int len, const float invLen,
    const int quad, const int l16) {
  f32x4 sacc[MT][MT];
  #pragma unroll
  for (int mq = 0; mq < MT; mq++)
    #pragma unroll
    for (int mk = 0; mk < MT; mk++) sacc[mq][mk] = (f32x4){0.f, 0.f, 0.f, 0.f};

  #pragma unroll
  for (int ks = 0; ks < 2; ks++) {
    s16x8 qa[MT], kb[MT];
    #pragma unroll
    for (int mq = 0; mq < MT; mq++)
      qa[mq] = *(const s16x8*)(QK2 + (size_t)idx_s[(mq << 4) + l16] * 1024
                               + (h << 6) + (ks << 5) + (quad << 3));
    #pragma unroll
    for (int mk = 0; mk < MT; mk++)
      kb[mk] = *(const s16x8*)(QK2 + (size_t)idx_s[(mk << 4) + l16] * 1024 + 512
                               + (h << 6) + (ks << 5) + (quad << 3));
    #pragma unroll
    for (int mq = 0; mq < MT; mq++)
      #pragma unroll
      for (int mk = 0; mk < MT; mk++)
        sacc[mq][mk] = mfma16(qa[mq], kb[mk], sacc[mq][mk]);
  }

  // mask columns m >= len
  #pragma unroll
  for (int mk = 0; mk < MT; mk++) {
    if (((mk << 4) + l16) >= len) {
      #pragma unroll
      for (int mq = 0; mq < MT; mq++)
        sacc[mq][mk] = (f32x4){-3e38f, -3e38f, -3e38f, -3e38f};
    }
  }

  // softmax per row: reduce across mk regs + 16 lanes
  #pragma unroll
  for (int mq = 0; mq < MT; mq++) {
    #pragma unroll
    for (int r = 0; r < 4; r++) {
      float mx = sacc[mq][0][r];
      #pragma unroll
      for (int mk = 1; mk < MT; mk++) mx = fmaxf(mx, sacc[mq][mk][r]);
      mx = fmaxf(mx, __shfl_xor(mx, 1));
      mx = fmaxf(mx, __shfl_xor(mx, 2));
      mx = fmaxf(mx, __shfl_xor(mx, 4));
      mx = fmaxf(mx, __shfl_xor(mx, 8));
      float sum = 0.f;
      #pragma unroll
      for (int mk = 0; mk < MT; mk++) {
        const float e = __expf((sacc[mq][mk][r] - mx) * 0.125f);
        sacc[mq][mk][r] = e; sum += e;
      }
      sum += __shfl_xor(sum, 1);
      sum += __shfl_xor(sum, 2);
      sum += __shfl_xor(sum, 4);
      sum += __shfl_xor(sum, 8);
      const float inv = 1.0f / sum;
      #pragma unroll
      for (int mk = 0; mk < MT; mk++) sacc[mq][mk][r] *= inv;
    }
  }

  // column sums over valid rows -> w[m]; combine quads via xor 16/32
  #pragma unroll
  for (int mk = 0; mk < MT; mk++) {
    float cs = 0.f;
    #pragma unroll
    for (int mq = 0; mq < MT; mq++)
      #pragma unroll
      for (int r = 0; r < 4; r++)
        cs += (((mq << 4) + (quad << 2) + r) < len) ? sacc[mq][mk][r] : 0.f;
    cs += __shfl_xor(cs, 16);
    cs += __shfl_xor(cs, 32);
    if (quad == 0) wl[(h << 6) + (mk << 4) + l16] = cs * invLen;
  }
}

// ---------------------------------------------------------------------------
// Launch 3: per-cell block; wave w handles heads 2w, 2w+1 (no barriers), then
// one sync and a cooperative xbar gather -> Xbar bf16 [c][6144].
// ---------------------------------------------------------------------------
__global__ __launch_bounds__(256)
void attn_pool(const u16* __restrict__ QK2, const u16* __restrict__ Xb,
               const int* __restrict__ cell_idx, const int* __restrict__ cell_len,
               u16* __restrict__ Xbar) {
  __shared__ int idx_s[64];
  __shared__ float wl[512];

  const int c = blockIdx.x;
  const int tid = threadIdx.x;
  const int wave = tid >> 6, lane = tid & 63;
  const int quad = lane >> 4, l16 = lane & 15;

  int len = cell_len[c];
  len = (len < 1) ? 1 : ((len > 64) ? 64 : len);
  const int mt = (len + 15) >> 4;
  const float invLen = 1.0f / (float)len;

  if (tid < 64) idx_s[tid] = cell_idx[(c << 6) + tid];
  __syncthreads();

  const int h0 = wave << 1;
  switch (mt) {
    case 1:
      head_sw<1>(QK2, idx_s, wl, h0,     len, invLen, quad, l16);
      head_sw<1>(QK2, idx_s, wl, h0 + 1, len, invLen, quad, l16);
      break;
    case 2:
      head_sw<2>(QK2, idx_s, wl, h0,     len, invLen, quad, l16);
      head_sw<2>(QK2, idx_s, wl, h0 + 1, len, invLen, quad, l16);
      break;
    case 3:
      head_sw<3>(QK2, idx_s, wl, h0,     len, invLen, quad, l16);
      head_sw<3>(QK2, idx_s, wl, h0 + 1, len, invLen, quad, l16);
      break;
    default:
      head_sw<4>(QK2, idx_s, wl, h0,     len, invLen, quad, l16);
      head_sw<4>(QK2, idx_s, wl, h0 + 1, len, invLen, quad, l16);
      break;
  }
  __syncthreads();

  // xbar: threads 0..191 each own 4 dims, all 8 heads
  if (tid < 192) {
    const int d0 = tid << 2;
    float acc[8][4];
    #pragma unroll
    for (int h = 0; h < 8; h++)
      #pragma unroll
      for (int d = 0; d < 4; d++) acc[h][d] = 0.f;
    for (int m = 0; m < len; m++) {
      const ushort4 xv = *(const ushort4*)(Xb + (size_t)idx_s[m] * 768 + d0);
      const float x0 = b2f(xv.x), x1 = b2f(xv.y), x2 = b2f(xv.z), x3 = b2f(xv.w);
      #pragma unroll
      for (int h = 0; h < 8; h++) {
        const float wv = wl[(h << 6) + m];
        acc[h][0] += wv * x0; acc[h][1] += wv * x1;
        acc[h][2] += wv * x2; acc[h][3] += wv * x3;
      }
    }
    #pragma unroll
    for (int h = 0; h < 8; h++) {
      ushort4 o;
      o.x = f2b(acc[h][0]); o.y = f2b(acc[h][1]);
      o.z = f2b(acc[h][2]); o.w = f2b(acc[h][3]);
      *(ushort4*)(Xbar + (size_t)c * 6144 + (h * 768) + d0) = o;
    }
  }
}

// ---------------------------------------------------------------------------
// Launch 4: K-split final GEMM. grid (4, 32, 6): z over K slices of 1024.
// ---------------------------------------------------------------------------
__global__ __launch_bounds__(256)
void gemm_final_ks(const u16* __restrict__ A, const u16* __restrict__ B,
                   float* __restrict__ partial) {
  __shared__ u16 As[64 * 32];
  __shared__ u16 Bs[64 * 32];
  const int tid = threadIdx.x;
  const int wave = tid >> 6, lane = tid & 63;
  const int quad = lane >> 4, l16 = lane & 15;
  const int m0 = blockIdx.y << 6, n0 = blockIdx.x << 6;
  const int z = blockIdx.z;

  const int r = lane >> 2, c8 = (lane & 3) << 3;
  const u16* gA = A + (size_t)(m0 + (wave << 4) + r) * 6144 + (z << 10) + c8;
  const u16* gB = B + (size_t)(n0 + (wave << 4) + r) * 6144 + (z << 10) + c8;
  u16* lA = As + (wave << 9);
  u16* lB = Bs + (wave << 9);

  f32x4 acc[4] = {{0,0,0,0},{0,0,0,0},{0,0,0,0},{0,0,0,0}};
  for (int k0 = 0; k0 < 1024; k0 += 32) {
    __syncthreads();
    gld_lds16(gA + k0, lA);
    gld_lds16(gB + k0, lB);
    __syncthreads();
    const s16x8 a = *(const s16x8*)(As + ((wave << 4) + l16) * 32 + (quad << 3));
    #pragma unroll
    for (int j = 0; j < 4; j++) {
      const s16x8 b = *(const s16x8*)(Bs + ((j << 4) + l16) * 32 + (quad << 3));
      acc[j] = mfma16(a, b, acc[j]);
    }
  }
  float* pz = partial + (size_t)z * 524288;
  const int row = m0 + (wave << 4) + (quad << 2);
  #pragma unroll
  for (int j = 0; j < 4; j++) {
    const int col = n0 + (j << 4) + l16;
    #pragma unroll
    for (int r2 = 0; r2 < 4; r2++)
      pz[(size_t)(row + r2) * 256 + col] = acc[j][r2];
  }
}

// Launch 5: out = sum_z partial[z] + b2
__global__ __launch_bounds__(256)
void reduce_out(const float* __restrict__ partial, const float* __restrict__ b2,
                float* __restrict__ out) {
  const size_t base = ((size_t)blockIdx.x * 256 + threadIdx.x) << 2;
  float4 s = *(const float4*)(partial + base);
  #pragma unroll
  for (int z = 1; z < 6; z++) {
    const float4 p = *(const float4*)(partial + (size_t)z * 524288 + base);
    s.x += p.x; s.y += p.y; s.z += p.z; s.w += p.w;
  }
  const int col = (int)(base & 255);
  const float4 bb = *(const float4*)(b2 + col);
  s.x += bb.x; s.y += bb.y; s.z += bb.z; s.w += bb.w;
  *(float4*)(out + base) = s;
}

// ---------------------------------------------------------------------------
extern "C" void kernel_launch(void* const* d_in, const int* in_sizes, int n_in,
                              void* d_out, int out_size, void* d_ws, size_t ws_size,
                              hipStream_t stream) {
  const float* chunk  = (const float*)d_in[0];
  const float* Wq     = (const float*)d_in[1];
  const float* bq     = (const float*)d_in[2];
  const float* Wk     = (const float*)d_in[3];
  const float* bk     = (const float*)d_in[4];
  const float* Wv     = (const float*)d_in[5];
  const float* bv     = (const float*)d_in[6];
  const float* W_in   = (const float*)d_in[7];
  const float* b_in   = (const float*)d_in[8];
  const float* Wo     = (const float*)d_in[9];
  const float* bo     = (const float*)d_in[10];
  const float* Wout   = (const float*)d_in[11];
  const float* bout   = (const float*)d_in[12];
  const int* cell_idx = (const int*)d_in[13];
  const int* cell_len = (const int*)d_in[14];

  // workspace layout (~224 MB; ws_size >= 237 MB verified)
  char* ws = (char*)d_ws;
  u16*   Wqkv    = (u16*)(ws + 0);              // [1024][768] bf16 (q|k fused)
  float* Wv_eff  = (float*)(ws + 1572864);      // [512][768] fp32
  float* Wf      = (float*)(ws + 3145728);      // [256][512] fp32 = Wout@Wo
  float* b_eff   = (float*)(ws + 3670016);      // [1024]
  float* b2      = (float*)(ws + 3674112);      // [256]
  u16*   Mh      = (u16*)(ws + 3675136);        // [256][6144] bf16
  u16*   Xbar    = (u16*)(ws + 6820864);        // [2048][6144] bf16
  u16*   Xb      = (u16*)(ws + 31986688);       // [50048][768] bf16
  u16*   QK2     = (u16*)(ws + 108860416);      // [50048][1024] bf16
  float* partial = (float*)(ws + 211358720);    // [6][2048][256] fp32

  dim3 blk(256);
  prep_all<<<dim3(2369), blk, 0, stream>>>(chunk, Wq, bq, Wk, bk, Wv, bv,
      W_in, b_in, Wo, bo, Wout, bout, Wqkv, Wv_eff, Wf, b_eff, b2, Xb);
  qk_mh<<<dim3(3512), blk, 0, stream>>>(Xb, Wqkv, b_eff, QK2, Wf, Wv_eff, Mh);
  attn_pool<<<dim3(2048), blk, 0, stream>>>(QK2, Xb, cell_idx, cell_len, Xbar);
  gemm_final_ks<<<dim3(4, 32, 6), blk, 0, stream>>>(Xbar, Mh, partial);
  reduce_out<<<dim3(512), blk, 0, stream>>>(partial, b2, (float*)d_out);
}